// Round 1
// baseline (484.549 us; speedup 1.0000x reference)
//
#include <hip/hip_runtime.h>
#include <hip/hip_bf16.h>

typedef float f32x4 __attribute__((ext_vector_type(4)));
typedef unsigned short u16x8 __attribute__((ext_vector_type(8)));
typedef __bf16 b16x8 __attribute__((ext_vector_type(8)));

static __device__ __forceinline__ unsigned short f2bf(float f) {
    unsigned int u = __builtin_bit_cast(unsigned int, f);
    return (unsigned short)((u + 0x7fffu + ((u >> 16) & 1u)) >> 16);
}

static __device__ __forceinline__ f32x4 mfma16(u16x8 a, u16x8 b, f32x4 c) {
    return __builtin_amdgcn_mfma_f32_16x16x32_bf16(
        __builtin_bit_cast(b16x8, a), __builtin_bit_cast(b16x8, b), c, 0, 0, 0);
}

// C[M,N] = (A[M,K] @ Bw[N,K]^T + bias) * scale
// Tile: 128(M) x 64(N), BK=32, 256 threads = 4 waves in 2x2 (wave tile 64x32).
template<bool A_BF16, bool OUT_F32>
__global__ __launch_bounds__(256)
void gemm_bt(const void* __restrict__ Ap, const float* __restrict__ Bw,
             const float* __restrict__ bias, void* __restrict__ Cp,
             int M, int N, int K, float scale)
{
    __shared__ unsigned short As[128][32];
    __shared__ unsigned short Bs[64][32];
    const int t = (int)threadIdx.x;
    const int wave = t >> 6, lane = t & 63;
    const int wr = wave >> 1, wc = wave & 1;
    const int lo = lane & 15, g = lane >> 4;
    const int brow = blockIdx.y * 128, bcol = blockIdx.x * 64;

    f32x4 acc[4][2] = {};

    for (int kt = 0; kt < K; kt += 32) {
        __syncthreads();   // protect previous iteration's LDS reads
        if constexpr (A_BF16) {
            const unsigned short* A = (const unsigned short*)Ap;
            #pragma unroll
            for (int i = 0; i < 2; ++i) {
                int idx = t + i * 256;          // 0..511, 16B each
                int row = idx >> 2, c8 = idx & 3;
                *reinterpret_cast<u16x8*>(&As[row][c8 * 8]) =
                    *reinterpret_cast<const u16x8*>(&A[(brow + row) * K + kt + c8 * 8]);
            }
        } else {
            const float* A = (const float*)Ap;
            #pragma unroll
            for (int i = 0; i < 4; ++i) {
                int idx = t + i * 256;          // 0..1023, float4 each
                int row = idx >> 3, c4 = idx & 7;
                f32x4 v = *reinterpret_cast<const f32x4*>(&A[(brow + row) * K + kt + c4 * 4]);
                ushort4 u;
                u.x = f2bf(v[0]); u.y = f2bf(v[1]); u.z = f2bf(v[2]); u.w = f2bf(v[3]);
                *reinterpret_cast<ushort4*>(&As[row][c4 * 4]) = u;
            }
        }
        #pragma unroll
        for (int i = 0; i < 2; ++i) {
            int idx = t + i * 256;              // 0..511, float4 each (64 rows x 8)
            int row = idx >> 3, c4 = idx & 7;
            f32x4 v = *reinterpret_cast<const f32x4*>(&Bw[(bcol + row) * K + kt + c4 * 4]);
            ushort4 u;
            u.x = f2bf(v[0]); u.y = f2bf(v[1]); u.z = f2bf(v[2]); u.w = f2bf(v[3]);
            *reinterpret_cast<ushort4*>(&Bs[row][c4 * 4]) = u;
        }
        __syncthreads();

        u16x8 af[4], bf[2];
        #pragma unroll
        for (int mf = 0; mf < 4; ++mf)
            af[mf] = *reinterpret_cast<const u16x8*>(&As[wr * 64 + mf * 16 + lo][g * 8]);
        #pragma unroll
        for (int nf = 0; nf < 2; ++nf)
            bf[nf] = *reinterpret_cast<const u16x8*>(&Bs[wc * 32 + nf * 16 + lo][g * 8]);
        #pragma unroll
        for (int mf = 0; mf < 4; ++mf)
            #pragma unroll
            for (int nf = 0; nf < 2; ++nf)
                acc[mf][nf] = mfma16(af[mf], bf[nf], acc[mf][nf]);
    }

    #pragma unroll
    for (int nf = 0; nf < 2; ++nf) {
        int col = bcol + wc * 32 + nf * 16 + lo;
        float bv = bias[col];
        #pragma unroll
        for (int mf = 0; mf < 4; ++mf) {
            #pragma unroll
            for (int j = 0; j < 4; ++j) {
                int row = brow + wr * 64 + mf * 16 + g * 4 + j;
                float v = (acc[mf][nf][j] + bv) * scale;
                if constexpr (OUT_F32)
                    ((float*)Cp)[row * N + col] = v;
                else
                    ((unsigned short*)Cp)[row * N + col] = f2bf(v);
            }
        }
    }
}

// Flash attention, non-causal. Q pre-scaled by 0.125*log2(e) so exp2 gives softmax.
// Block: 1 head x 128 q-rows, 4 waves (32 q-rows each). Key tiles of 32.
__global__ __launch_bounds__(256)
void attn_kernel(const unsigned short* __restrict__ Q,
                 const unsigned short* __restrict__ Kg,
                 const unsigned short* __restrict__ V,
                 unsigned short* __restrict__ Ctx)
{
    __shared__ unsigned short VT[64][32];       // VT[d][k] = V[kt+k][h*64+d]
    __shared__ unsigned short P[4][32][40];     // per-wave P tile, padded
    const int t = (int)threadIdx.x;
    const int w = t >> 6, lane = t & 63;
    const int lo = lane & 15, g = lane >> 4;
    const int h = blockIdx.y;
    const int qrow = blockIdx.x * 128 + w * 32;
    const int hc = h * 64;

    u16x8 qf[2][2];
    #pragma unroll
    for (int mf = 0; mf < 2; ++mf)
        #pragma unroll
        for (int kf = 0; kf < 2; ++kf)
            qf[mf][kf] = *reinterpret_cast<const u16x8*>(
                &Q[(qrow + mf * 16 + lo) * 1024 + hc + kf * 32 + g * 8]);

    float m[2][4], lsum[2][4];
    f32x4 o[2][4] = {};
    #pragma unroll
    for (int mf = 0; mf < 2; ++mf)
        #pragma unroll
        for (int j = 0; j < 4; ++j) { m[mf][j] = -1e30f; lsum[mf][j] = 0.f; }

    const int sk = t & 31, sd = (t >> 5) * 8;

    for (int kt = 0; kt < 4096; kt += 32) {
        // issue global loads early (latency overlap with barrier)
        u16x8 vv = *reinterpret_cast<const u16x8*>(&V[(kt + sk) * 1024 + hc + sd]);
        u16x8 kfr[2][2];
        #pragma unroll
        for (int nf = 0; nf < 2; ++nf)
            #pragma unroll
            for (int kf = 0; kf < 2; ++kf)
                kfr[nf][kf] = *reinterpret_cast<const u16x8*>(
                    &Kg[(kt + nf * 16 + lo) * 1024 + hc + kf * 32 + g * 8]);

        __syncthreads();   // all waves done reading previous VT
        #pragma unroll
        for (int j = 0; j < 8; ++j)
            VT[sd + j][sk] = vv[j];
        __syncthreads();   // VT ready

        // S = Q K^T  (scores already in log2e units)
        f32x4 s[2][2] = {};
        #pragma unroll
        for (int kf = 0; kf < 2; ++kf)
            #pragma unroll
            for (int mf = 0; mf < 2; ++mf)
                #pragma unroll
                for (int nf = 0; nf < 2; ++nf)
                    s[mf][nf] = mfma16(qf[mf][kf], kfr[nf][kf], s[mf][nf]);

        // online softmax; row r = 4g+j (+16 mf); reduce across lanes 0..15 of group
        float scl[2][4];
        #pragma unroll
        for (int mf = 0; mf < 2; ++mf) {
            #pragma unroll
            for (int j = 0; j < 4; ++j) {
                float mx = fmaxf(s[mf][0][j], s[mf][1][j]);
                mx = fmaxf(mx, __shfl_xor(mx, 1));
                mx = fmaxf(mx, __shfl_xor(mx, 2));
                mx = fmaxf(mx, __shfl_xor(mx, 4));
                mx = fmaxf(mx, __shfl_xor(mx, 8));
                float mn = fmaxf(m[mf][j], mx);
                float sc = __builtin_amdgcn_exp2f(m[mf][j] - mn);
                float p0 = __builtin_amdgcn_exp2f(s[mf][0][j] - mn);
                float p1 = __builtin_amdgcn_exp2f(s[mf][1][j] - mn);
                P[w][mf * 16 + g * 4 + j][lo]      = f2bf(p0);
                P[w][mf * 16 + g * 4 + j][16 + lo] = f2bf(p1);
                float ps = p0 + p1;
                ps += __shfl_xor(ps, 1);
                ps += __shfl_xor(ps, 2);
                ps += __shfl_xor(ps, 4);
                ps += __shfl_xor(ps, 8);
                lsum[mf][j] = lsum[mf][j] * sc + ps;
                m[mf][j] = mn;
                scl[mf][j] = sc;
            }
        }
        // rescale accumulator
        #pragma unroll
        for (int mf = 0; mf < 2; ++mf)
            #pragma unroll
            for (int nf = 0; nf < 4; ++nf)
                #pragma unroll
                for (int j = 0; j < 4; ++j)
                    o[mf][nf][j] *= scl[mf][j];
        // O += P * V
        #pragma unroll
        for (int mf = 0; mf < 2; ++mf) {
            u16x8 pa = *reinterpret_cast<const u16x8*>(&P[w][mf * 16 + lo][g * 8]);
            #pragma unroll
            for (int nf = 0; nf < 4; ++nf) {
                u16x8 vb = *reinterpret_cast<const u16x8*>(&VT[nf * 16 + lo][g * 8]);
                o[mf][nf] = mfma16(pa, vb, o[mf][nf]);
            }
        }
    }

    #pragma unroll
    for (int mf = 0; mf < 2; ++mf) {
        #pragma unroll
        for (int j = 0; j < 4; ++j) {
            float inv = 1.f / lsum[mf][j];
            int row = qrow + mf * 16 + g * 4 + j;
            #pragma unroll
            for (int nf = 0; nf < 4; ++nf)
                Ctx[row * 1024 + hc + nf * 16 + lo] = f2bf(o[mf][nf][j] * inv);
        }
    }
}

extern "C" void kernel_launch(void* const* d_in, const int* in_sizes, int n_in,
                              void* d_out, int out_size, void* d_ws, size_t ws_size,
                              hipStream_t stream)
{
    const float* x  = (const float*)d_in[0];
    const float* Wq = (const float*)d_in[1];
    const float* bq = (const float*)d_in[2];
    const float* Wk = (const float*)d_in[3];
    const float* bk = (const float*)d_in[4];
    const float* Wv = (const float*)d_in[5];
    const float* bv = (const float*)d_in[6];
    const float* Wo = (const float*)d_in[7];
    const float* bo = (const float*)d_in[8];
    float* out = (float*)d_out;

    const int S = 4096, HID = 1024;
    unsigned short* qws = (unsigned short*)d_ws;
    unsigned short* kws = qws + (size_t)S * HID;
    unsigned short* vws = kws + (size_t)S * HID;
    unsigned short* cws = vws + (size_t)S * HID;

    const float qscale = 0.125f * 1.44269504088896f;  // 1/sqrt(64) * log2(e)
    dim3 gg(HID / 64, S / 128);

    gemm_bt<false, false><<<gg, 256, 0, stream>>>(x, Wq, bq, qws, S, HID, HID, qscale);
    gemm_bt<false, false><<<gg, 256, 0, stream>>>(x, Wk, bk, kws, S, HID, HID, 1.0f);
    gemm_bt<false, false><<<gg, 256, 0, stream>>>(x, Wv, bv, vws, S, HID, HID, 1.0f);

    dim3 ga(S / 128, 16);
    attn_kernel<<<ga, 256, 0, stream>>>(qws, kws, vws, cws);

    gemm_bt<true, true><<<gg, 256, 0, stream>>>(cws, Wo, bo, out, S, HID, HID, 1.0f);
}

// Round 2
// 313.989 us; speedup vs baseline: 1.5432x; 1.5432x over previous
//
#include <hip/hip_runtime.h>
#include <hip/hip_bf16.h>

typedef float f32x4 __attribute__((ext_vector_type(4)));
typedef unsigned short u16x8 __attribute__((ext_vector_type(8)));
typedef __bf16 b16x8 __attribute__((ext_vector_type(8)));

static __device__ __forceinline__ unsigned short f2bf(float f) {
    unsigned int u = __builtin_bit_cast(unsigned int, f);
    return (unsigned short)((u + 0x7fffu + ((u >> 16) & 1u)) >> 16);
}

static __device__ __forceinline__ unsigned int pkbf(float a, float b) {
    unsigned short x = __builtin_bit_cast(unsigned short, (__bf16)a);
    unsigned short y = __builtin_bit_cast(unsigned short, (__bf16)b);
    return (unsigned int)x | ((unsigned int)y << 16);
}

static __device__ __forceinline__ f32x4 mfma16(u16x8 a, u16x8 b, f32x4 c) {
    return __builtin_amdgcn_mfma_f32_16x16x32_bf16(
        __builtin_bit_cast(b16x8, a), __builtin_bit_cast(b16x8, b), c, 0, 0, 0);
}

// C[M,N] = (A[M,K] @ Bw[N,K]^T + bias) * scale
// Tile: 128(M) x 64(N), BK=32, 256 threads = 4 waves in 2x2 (wave tile 64x32).
template<bool A_BF16, bool OUT_F32>
__global__ __launch_bounds__(256)
void gemm_bt(const void* __restrict__ Ap, const float* __restrict__ Bw,
             const float* __restrict__ bias, void* __restrict__ Cp,
             int M, int N, int K, float scale)
{
    __shared__ unsigned short As[128][32];
    __shared__ unsigned short Bs[64][32];
    const int t = (int)threadIdx.x;
    const int wave = t >> 6, lane = t & 63;
    const int wr = wave >> 1, wc = wave & 1;
    const int lo = lane & 15, g = lane >> 4;
    const int brow = blockIdx.y * 128, bcol = blockIdx.x * 64;

    f32x4 acc[4][2] = {};

    for (int kt = 0; kt < K; kt += 32) {
        __syncthreads();
        if constexpr (A_BF16) {
            const unsigned short* A = (const unsigned short*)Ap;
            #pragma unroll
            for (int i = 0; i < 2; ++i) {
                int idx = t + i * 256;
                int row = idx >> 2, c8 = idx & 3;
                *reinterpret_cast<u16x8*>(&As[row][c8 * 8]) =
                    *reinterpret_cast<const u16x8*>(&A[(brow + row) * K + kt + c8 * 8]);
            }
        } else {
            const float* A = (const float*)Ap;
            #pragma unroll
            for (int i = 0; i < 4; ++i) {
                int idx = t + i * 256;
                int row = idx >> 3, c4 = idx & 7;
                f32x4 v = *reinterpret_cast<const f32x4*>(&A[(brow + row) * K + kt + c4 * 4]);
                ushort4 u;
                u.x = f2bf(v[0]); u.y = f2bf(v[1]); u.z = f2bf(v[2]); u.w = f2bf(v[3]);
                *reinterpret_cast<ushort4*>(&As[row][c4 * 4]) = u;
            }
        }
        #pragma unroll
        for (int i = 0; i < 2; ++i) {
            int idx = t + i * 256;
            int row = idx >> 3, c4 = idx & 7;
            f32x4 v = *reinterpret_cast<const f32x4*>(&Bw[(bcol + row) * K + kt + c4 * 4]);
            ushort4 u;
            u.x = f2bf(v[0]); u.y = f2bf(v[1]); u.z = f2bf(v[2]); u.w = f2bf(v[3]);
            *reinterpret_cast<ushort4*>(&Bs[row][c4 * 4]) = u;
        }
        __syncthreads();

        u16x8 af[4], bf[2];
        #pragma unroll
        for (int mf = 0; mf < 4; ++mf)
            af[mf] = *reinterpret_cast<const u16x8*>(&As[wr * 64 + mf * 16 + lo][g * 8]);
        #pragma unroll
        for (int nf = 0; nf < 2; ++nf)
            bf[nf] = *reinterpret_cast<const u16x8*>(&Bs[wc * 32 + nf * 16 + lo][g * 8]);
        #pragma unroll
        for (int mf = 0; mf < 4; ++mf)
            #pragma unroll
            for (int nf = 0; nf < 2; ++nf)
                acc[mf][nf] = mfma16(af[mf], bf[nf], acc[mf][nf]);
    }

    #pragma unroll
    for (int nf = 0; nf < 2; ++nf) {
        int col = bcol + wc * 32 + nf * 16 + lo;
        float bv = bias[col];
        #pragma unroll
        for (int mf = 0; mf < 4; ++mf) {
            #pragma unroll
            for (int j = 0; j < 4; ++j) {
                int row = brow + wr * 64 + mf * 16 + g * 4 + j;
                float v = (acc[mf][nf][j] + bv) * scale;
                if constexpr (OUT_F32)
                    ((float*)Cp)[row * N + col] = v;
                else
                    ((unsigned short*)Cp)[row * N + col] = f2bf(v);
            }
        }
    }
}

// Flash attention, non-causal, swapped QK^T (S^T = K Q^T) so softmax row-reduce
// is lane-local. Q pre-scaled by 0.125*log2(e) -> exp2 softmax.
// Block: 1 head x 128 q-rows, 4 waves (32 q-rows each). Key tiles of 64.
__global__ __launch_bounds__(256)
void attn_kernel(const unsigned short* __restrict__ Q,
                 const unsigned short* __restrict__ Kg,
                 const unsigned short* __restrict__ V,
                 unsigned short* __restrict__ Ctx)
{
    __shared__ unsigned short VT[64][72];      // VT[d][key], pad 72 (144B: 16B-aligned, stride=4 banks)
    __shared__ unsigned short Pl[4][32][72];   // per-wave P[qrow][key]
    const int t = (int)threadIdx.x;
    const int w = t >> 6, lane = t & 63;
    const int lo = lane & 15, g = lane >> 4;
    const int hc = blockIdx.y * 64;
    const int qbase = blockIdx.x * 128 + w * 32;

    // Q as B-fragments: lane holds Q[qrow=lo][d = kf*32 + g*8 .. +8]
    u16x8 qf[2][2];
    #pragma unroll
    for (int qn = 0; qn < 2; ++qn)
        #pragma unroll
        for (int kf = 0; kf < 2; ++kf)
            qf[qn][kf] = *reinterpret_cast<const u16x8*>(
                &Q[(qbase + qn * 16 + lo) * 1024 + hc + kf * 32 + g * 8]);

    float m[2] = {-1e30f, -1e30f}, lsum[2] = {0.f, 0.f};
    f32x4 o[2][4] = {};

    const int vkey = lane;      // stage V: wave w covers d rows w*8..+8 (+32)
    const int vd = w * 8;

    for (int kt = 0; kt < 4096; kt += 64) {
        // prefetch V + K fragments for this tile (global, L2-resident)
        u16x8 vv0 = *reinterpret_cast<const u16x8*>(&V[(size_t)(kt + vkey) * 1024 + hc + vd]);
        u16x8 vv1 = *reinterpret_cast<const u16x8*>(&V[(size_t)(kt + vkey) * 1024 + hc + vd + 32]);
        u16x8 kfr[4][2];
        #pragma unroll
        for (int ks = 0; ks < 4; ++ks)
            #pragma unroll
            for (int kf = 0; kf < 2; ++kf)
                kfr[ks][kf] = *reinterpret_cast<const u16x8*>(
                    &Kg[(size_t)(kt + ks * 16 + lo) * 1024 + hc + kf * 32 + g * 8]);

        __syncthreads();               // all waves done reading previous VT
        #pragma unroll
        for (int j = 0; j < 8; ++j) {
            VT[vd + j][vkey] = vv0[j];
            VT[vd + 32 + j][vkey] = vv1[j];
        }
        __syncthreads();               // VT ready

        // S^T[key, qrow]: lane holds keys {ks*16 + g*4 + j} for qrow = qn*16+lo
        f32x4 s[4][2] = {};
        #pragma unroll
        for (int kf = 0; kf < 2; ++kf)
            #pragma unroll
            for (int ks = 0; ks < 4; ++ks)
                #pragma unroll
                for (int qn = 0; qn < 2; ++qn)
                    s[ks][qn] = mfma16(kfr[ks][kf], qf[qn][kf], s[ks][qn]);

        // online softmax: in-lane max over 16 keys + 2 shuffles
        float mx[2];
        #pragma unroll
        for (int qn = 0; qn < 2; ++qn) {
            float v = s[0][qn][0];
            #pragma unroll
            for (int ks = 0; ks < 4; ++ks)
                #pragma unroll
                for (int j = 0; j < 4; ++j)
                    v = fmaxf(v, s[ks][qn][j]);
            v = fmaxf(v, __shfl_xor(v, 16));
            v = fmaxf(v, __shfl_xor(v, 32));
            mx[qn] = v;
        }
        bool defer = (mx[0] - m[0] <= 8.f) && (mx[1] - m[1] <= 8.f);
        if (!__all(defer)) {
            float scl[2];
            #pragma unroll
            for (int qn = 0; qn < 2; ++qn) {
                float mn = fmaxf(m[qn], mx[qn]);
                scl[qn] = __builtin_amdgcn_exp2f(m[qn] - mn);
                m[qn] = mn;
                lsum[qn] *= scl[qn];
            }
            // o rows live at qrow = qm*16 + g*4 + j: fetch that row's scale
            #pragma unroll
            for (int qm = 0; qm < 2; ++qm)
                #pragma unroll
                for (int j = 0; j < 4; ++j) {
                    float sj = __shfl(scl[qm], (g << 4) | (g * 4 + j));
                    #pragma unroll
                    for (int nf = 0; nf < 4; ++nf)
                        o[qm][nf][j] *= sj;
                }
        }

        // P = exp2(S - m), store bf16 to per-wave LDS, accumulate row sums
        #pragma unroll
        for (int qn = 0; qn < 2; ++qn) {
            float ps = 0.f;
            #pragma unroll
            for (int ks = 0; ks < 4; ++ks) {
                float p0 = __builtin_amdgcn_exp2f(s[ks][qn][0] - m[qn]);
                float p1 = __builtin_amdgcn_exp2f(s[ks][qn][1] - m[qn]);
                float p2 = __builtin_amdgcn_exp2f(s[ks][qn][2] - m[qn]);
                float p3 = __builtin_amdgcn_exp2f(s[ks][qn][3] - m[qn]);
                ps += (p0 + p1) + (p2 + p3);
                unsigned int* dst = reinterpret_cast<unsigned int*>(
                    &Pl[w][qn * 16 + lo][ks * 16 + g * 4]);
                dst[0] = pkbf(p0, p1);
                dst[1] = pkbf(p2, p3);
            }
            ps += __shfl_xor(ps, 16);
            ps += __shfl_xor(ps, 32);
            lsum[qn] += ps;
        }

        // O += P V : A-frags from Pl, B-frags from VT
        u16x8 pa[2][2], vb[2][4];
        #pragma unroll
        for (int qm = 0; qm < 2; ++qm)
            #pragma unroll
            for (int kf = 0; kf < 2; ++kf)
                pa[qm][kf] = *reinterpret_cast<const u16x8*>(
                    &Pl[w][qm * 16 + lo][kf * 32 + g * 8]);
        #pragma unroll
        for (int kf = 0; kf < 2; ++kf)
            #pragma unroll
            for (int nf = 0; nf < 4; ++nf)
                vb[kf][nf] = *reinterpret_cast<const u16x8*>(
                    &VT[nf * 16 + lo][kf * 32 + g * 8]);
        #pragma unroll
        for (int kf = 0; kf < 2; ++kf)
            #pragma unroll
            for (int qm = 0; qm < 2; ++qm)
                #pragma unroll
                for (int nf = 0; nf < 4; ++nf)
                    o[qm][nf] = mfma16(pa[qm][kf], vb[kf][nf], o[qm][nf]);
    }

    // epilogue: normalize rows (row = qm*16 + g*4 + j) and store bf16 ctx
    #pragma unroll
    for (int qm = 0; qm < 2; ++qm) {
        float linv = 1.f / lsum[qm];
        #pragma unroll
        for (int j = 0; j < 4; ++j) {
            float lj = __shfl(linv, (g << 4) | (g * 4 + j));
            int row = qbase + qm * 16 + g * 4 + j;
            #pragma unroll
            for (int nf = 0; nf < 4; ++nf)
                Ctx[(size_t)row * 1024 + hc + nf * 16 + lo] = f2bf(o[qm][nf][j] * lj);
        }
    }
}

extern "C" void kernel_launch(void* const* d_in, const int* in_sizes, int n_in,
                              void* d_out, int out_size, void* d_ws, size_t ws_size,
                              hipStream_t stream)
{
    const float* x  = (const float*)d_in[0];
    const float* Wq = (const float*)d_in[1];
    const float* bq = (const float*)d_in[2];
    const float* Wk = (const float*)d_in[3];
    const float* bk = (const float*)d_in[4];
    const float* Wv = (const float*)d_in[5];
    const float* bv = (const float*)d_in[6];
    const float* Wo = (const float*)d_in[7];
    const float* bo = (const float*)d_in[8];
    float* out = (float*)d_out;

    const int S = 4096, HID = 1024;
    unsigned short* qws = (unsigned short*)d_ws;
    unsigned short* kws = qws + (size_t)S * HID;
    unsigned short* vws = kws + (size_t)S * HID;
    unsigned short* cws = vws + (size_t)S * HID;

    const float qscale = 0.125f * 1.44269504088896f;  // 1/sqrt(64) * log2(e)
    dim3 gg(HID / 64, S / 128);

    gemm_bt<false, false><<<gg, 256, 0, stream>>>(x, Wq, bq, qws, S, HID, HID, qscale);
    gemm_bt<false, false><<<gg, 256, 0, stream>>>(x, Wk, bk, kws, S, HID, HID, 1.0f);
    gemm_bt<false, false><<<gg, 256, 0, stream>>>(x, Wv, bv, vws, S, HID, HID, 1.0f);

    dim3 ga(S / 128, 16);
    attn_kernel<<<ga, 256, 0, stream>>>(qws, kws, vws, cws);

    gemm_bt<true, true><<<gg, 256, 0, stream>>>(cws, Wo, bo, out, S, HID, HID, 1.0f);
}